// Round 1
// baseline (197.527 us; speedup 1.0000x reference)
//
#include <hip/hip_runtime.h>

typedef __attribute__((ext_vector_type(4))) float f32x4;
typedef __attribute__((ext_vector_type(8))) short bf16x8;

#define NEG_INF_F (-1000000000.0f)

__device__ inline short f2bf(float f) {
    union { float f; unsigned u; } v; v.f = f;
    unsigned r = v.u + 0x7fffu + ((v.u >> 16) & 1u);
    return (short)(r >> 16);
}

// One block = 4 waves = one (b,h) and one 64-row Q tile.
// Wave w owns q rows [qt*64 + w*16, +16).
// S^T = K * Q^T via mfma_f32_16x16x32_bf16:
//   A = K rows (16 keys x 32 d), B = Q^T (32 d x 16 q)
//   C: col = lane&15 -> q, row = (lane>>4)*4+j -> key  (guide m89 layout)
// O^T = V2^T * P^T (same intrinsic), gate^T = W * am^T in epilogue.
__global__ __launch_bounds__(256) void aoa_attn_kernel(
    const float* __restrict__ gv,
    const float* __restrict__ q2,
    const float* __restrict__ keyp,
    const int*   __restrict__ maskp,
    const float* __restrict__ v1,
    const float* __restrict__ v2,
    const float* __restrict__ W,
    const float* __restrict__ bch,
    float* __restrict__ out)
{
    constexpr int S = 1024, D = 64;
    const int bh  = blockIdx.x;   // 0..63  (b*8 + h)
    const int qt  = blockIdx.y;   // 0..15
    const int b   = bh >> 3;
    const int tid = threadIdx.x;
    const int wid = tid >> 6;
    const int lane = tid & 63;
    const int l15 = lane & 15;
    const int l4  = lane >> 4;

    float* out_attn = out + 512;

    if (bh == 0 && qt == 0) {
        // gv_feat passthrough (512 f32)
        out[tid]       = gv[tid];
        out[tid + 256] = gv[tid + 256];
    }

    __shared__ int   mask_lds[S];
    __shared__ short P_lds[4][64][17];   // per-wave P^T staging, padded

    for (int i = tid; i < S; i += 256) mask_lds[i] = maskp[b * S + i];
    __syncthreads();

    const size_t base = (size_t)bh * S * D;
    const float* Qp  = q2  + base;
    const float* Kp  = keyp + base;
    const float* V1p = v1  + base;
    const float* V2p = v2  + base;

    const int qrow = qt * 64 + wid * 16 + l15;   // this lane's q (column role)

    // Hoisted Q B-fragments: bq[ds][j] = Q[qrow][ds*32 + l4*8 + j]
    bf16x8 bq[2];
    #pragma unroll
    for (int ds = 0; ds < 2; ++ds) {
        const float* p = Qp + (size_t)qrow * D + ds * 32 + l4 * 8;
        #pragma unroll
        for (int j = 0; j < 8; ++j) bq[ds][j] = f2bf(p[j]);
    }

    f32x4 acc_o[4];
    #pragma unroll
    for (int i = 0; i < 4; ++i) acc_o[i] = (f32x4){0.f, 0.f, 0.f, 0.f};
    float m_run = -1e30f, l_run = 0.0f;
    const float scaling = 0.125f;   // D^-0.5

    for (int kt = 0; kt < S; kt += 64) {
        // ---- scores S^T tile (64 keys x 16 q per wave) ----
        f32x4 accs[4];
        #pragma unroll
        for (int kb = 0; kb < 4; ++kb) {
            f32x4 a = (f32x4){0.f, 0.f, 0.f, 0.f};
            #pragma unroll
            for (int ds = 0; ds < 2; ++ds) {
                bf16x8 ak;
                const float* p = Kp + (size_t)(kt + kb * 16 + l15) * D + ds * 32 + l4 * 8;
                #pragma unroll
                for (int j = 0; j < 8; ++j) ak[j] = f2bf(p[j]);
                a = __builtin_amdgcn_mfma_f32_16x16x32_bf16(ak, bq[ds], a, 0, 0, 0);
            }
            accs[kb] = a;
        }

        // ---- mask + scale + online softmax (16 keys in-lane, 4 lanes per q) ----
        float s[16];
        float tmax = -1e30f;
        #pragma unroll
        for (int kb = 0; kb < 4; ++kb)
            #pragma unroll
            for (int jj = 0; jj < 4; ++jj) {
                int kk = kt + kb * 16 + l4 * 4 + jj;
                float val = mask_lds[kk] ? accs[kb][jj] * scaling : NEG_INF_F;
                s[kb * 4 + jj] = val;
                tmax = fmaxf(tmax, val);
            }
        tmax = fmaxf(tmax, __shfl_xor(tmax, 16));
        tmax = fmaxf(tmax, __shfl_xor(tmax, 32));
        float mnew = fmaxf(m_run, tmax);
        float resc = __expf(m_run - mnew);
        float psum = 0.f;
        short pb[16];
        #pragma unroll
        for (int i = 0; i < 16; ++i) {
            float p = __expf(s[i] - mnew);
            psum += p;
            pb[i] = f2bf(p);
        }
        psum += __shfl_xor(psum, 16);
        psum += __shfl_xor(psum, 32);
        l_run = l_run * resc + psum;
        m_run = mnew;
        #pragma unroll
        for (int db = 0; db < 4; ++db)
            #pragma unroll
            for (int jj = 0; jj < 4; ++jj) acc_o[db][jj] *= resc;

        // ---- P^T to per-wave LDS (key-major), then load B-fragments ----
        #pragma unroll
        for (int kb = 0; kb < 4; ++kb)
            #pragma unroll
            for (int jj = 0; jj < 4; ++jj)
                P_lds[wid][kb * 16 + l4 * 4 + jj][l15] = pb[kb * 4 + jj];

        bf16x8 bp[2];
        #pragma unroll
        for (int ks = 0; ks < 2; ++ks)
            #pragma unroll
            for (int j = 0; j < 8; ++j)
                bp[ks][j] = P_lds[wid][ks * 32 + l4 * 8 + j][l15];

        // ---- O^T += V2^T * P^T ----
        #pragma unroll
        for (int db = 0; db < 4; ++db) {
            #pragma unroll
            for (int ks = 0; ks < 2; ++ks) {
                bf16x8 av;
                #pragma unroll
                for (int j = 0; j < 8; ++j)
                    av[j] = f2bf(V2p[(size_t)(kt + ks * 32 + l4 * 8 + j) * D + db * 16 + l15]);
                acc_o[db] = __builtin_amdgcn_mfma_f32_16x16x32_bf16(av, bp[ks], acc_o[db], 0, 0, 0);
            }
        }
    }

    // ---- channel gate: gate^T[e][q] = sum_d W[e][d] * (v1[q][d]*key[q][d]) ----
    f32x4 acc_g[4];
    #pragma unroll
    for (int i = 0; i < 4; ++i) acc_g[i] = (f32x4){0.f, 0.f, 0.f, 0.f};

    bf16x8 bam[2];
    #pragma unroll
    for (int ds = 0; ds < 2; ++ds) {
        const float* p1 = V1p + (size_t)qrow * D + ds * 32 + l4 * 8;
        const float* pk = Kp  + (size_t)qrow * D + ds * 32 + l4 * 8;
        #pragma unroll
        for (int j = 0; j < 8; ++j) bam[ds][j] = f2bf(p1[j] * pk[j]);
    }
    #pragma unroll
    for (int eb = 0; eb < 4; ++eb) {
        #pragma unroll
        for (int ds = 0; ds < 2; ++ds) {
            bf16x8 aw;
            const float* pw = W + (size_t)(eb * 16 + l15) * D + ds * 32 + l4 * 8;
            #pragma unroll
            for (int j = 0; j < 8; ++j) aw[j] = f2bf(pw[j]);
            acc_g[eb] = __builtin_amdgcn_mfma_f32_16x16x32_bf16(aw, bam[ds], acc_g[eb], 0, 0, 0);
        }
    }

    // ---- epilogue: out = (O / l) * sigmoid(gate + b) ----
    float inv_l = 1.0f / l_run;
    #pragma unroll
    for (int db = 0; db < 4; ++db)
        #pragma unroll
        for (int jj = 0; jj < 4; ++jj) {
            int d = db * 16 + l4 * 4 + jj;
            float o = acc_o[db][jj] * inv_l;
            float z = acc_g[db][jj] + bch[d];
            float gate = 1.0f / (1.0f + __expf(-z));
            out_attn[base + (size_t)qrow * D + d] = o * gate;
        }
}

extern "C" void kernel_launch(void* const* d_in, const int* in_sizes, int n_in,
                              void* d_out, int out_size, void* d_ws, size_t ws_size,
                              hipStream_t stream) {
    const float* gv   = (const float*)d_in[0];
    const float* q2   = (const float*)d_in[1];
    const float* keyp = (const float*)d_in[2];
    const int*   mask = (const int*)  d_in[3];
    const float* v1   = (const float*)d_in[4];
    const float* v2   = (const float*)d_in[5];
    const float* W    = (const float*)d_in[6];
    const float* bch  = (const float*)d_in[7];
    float* out = (float*)d_out;

    dim3 grid(64, 16);   // (b*h, q-tile)
    aoa_attn_kernel<<<grid, 256, 0, stream>>>(gv, q2, keyp, mask, v1, v2, W, bch, out);
}

// Round 2
// 76.214 us; speedup vs baseline: 2.5918x; 2.5918x over previous
//
#include <hip/hip_runtime.h>

typedef __attribute__((ext_vector_type(4))) float f32x4;
typedef __attribute__((ext_vector_type(8))) short bf16x8;
typedef __attribute__((ext_vector_type(4))) short s16x4;

#define NEG_INF_F (-1000000000.0f)

__device__ inline short f2bf(float f) {
    union { float f; unsigned u; } v; v.f = f;
    unsigned r = v.u + 0x7fffu + ((v.u >> 16) & 1u);
    return (short)(r >> 16);
}

// One block = 4 waves = one (b,h), one 64-row Q tile.
// Orientation (as R1, verified): S^T = K*Q^T ; O^T = V2^T*P^T ; gate^T = W*am^T
//   mfma_f32_16x16x32_bf16 C layout: col=lane&15, row=(lane>>4)*4+j
// R2: K and V2^T staged in LDS as bf16 (stride 72 shorts = 144B -> conflict-free b128),
//     P staged q-major so write=b64, read=b128.
__global__ __launch_bounds__(256) void aoa_attn_kernel(
    const float* __restrict__ gv,
    const float* __restrict__ q2,
    const float* __restrict__ keyp,
    const int*   __restrict__ maskp,
    const float* __restrict__ v1,
    const float* __restrict__ v2,
    const float* __restrict__ W,
    const float* __restrict__ bch,
    float* __restrict__ out)
{
    constexpr int S = 1024, D = 64;
    const int bh  = blockIdx.x;   // b*8 + h
    const int qt  = blockIdx.y;   // 0..15
    const int b   = bh >> 3;
    const int tid = threadIdx.x;
    const int wid = tid >> 6;
    const int lane = tid & 63;
    const int l15 = lane & 15;
    const int l4  = lane >> 4;

    float* out_attn = out + 512;

    if (bh == 0 && qt == 0) {
        out[tid]       = gv[tid];
        out[tid + 256] = gv[tid + 256];
    }

    __shared__ float maskf[S];                 // 0 or NEG_INF
    __shared__ short K_lds[64][72];            // [key_local][d], 144B stride
    __shared__ short Vt_lds[64][72];           // [d][key_local]
    __shared__ short P2[4][16][72];            // per-wave, [q_local][key_local]

    for (int i = tid; i < S; i += 256)
        maskf[i] = maskp[b * S + i] ? 0.0f : NEG_INF_F;

    const size_t base = (size_t)bh * S * D;
    const float* Qp  = q2   + base;
    const float* Kp  = keyp + base;
    const float* V1p = v1   + base;
    const float* V2p = v2   + base;

    const int qrow = qt * 64 + wid * 16 + l15;   // this lane's q (column role)

    // Hoisted Q B-fragments: bq[ds][j] = Q[qrow][ds*32 + l4*8 + j]
    bf16x8 bq[2];
    #pragma unroll
    for (int ds = 0; ds < 2; ++ds) {
        const float4* p = (const float4*)(Qp + (size_t)qrow * D + ds * 32 + l4 * 8);
        float4 x0 = p[0], x1 = p[1];
        float xs[8];
        *(float4*)&xs[0] = x0; *(float4*)&xs[4] = x1;
        #pragma unroll
        for (int j = 0; j < 8; ++j) bq[ds][j] = f2bf(xs[j]);
    }

    f32x4 acc_o[4];
    #pragma unroll
    for (int i = 0; i < 4; ++i) acc_o[i] = (f32x4){0.f, 0.f, 0.f, 0.f};
    float m_run = -1e30f, l_run = 0.0f;
    const float scaling = 0.125f;   // D^-0.5

    // staging index precompute
    const int kr  = tid >> 2;          // 0..63  K row
    const int ksg = tid & 3;           // 0..3   K col segment (16 floats)
    const int k2  = tid >> 3;          // 0..31  V2 key pair
    const int dg  = tid & 7;           // 0..7   V2 d-group (8 d)

    for (int kt = 0; kt < S; kt += 64) {
        __syncthreads();   // previous tile fully consumed

        // ---- stage K tile: K_lds[k][d] = bf16(K[kt+k][d]) ----
        {
            const float4* src = (const float4*)(Kp + (size_t)(kt + kr) * D + ksg * 16);
            float4 a0 = src[0], a1 = src[1], a2 = src[2], a3 = src[3];
            float xs[16];
            *(float4*)&xs[0]  = a0; *(float4*)&xs[4]  = a1;
            *(float4*)&xs[8]  = a2; *(float4*)&xs[12] = a3;
            bf16x8 w0, w1;
            #pragma unroll
            for (int j = 0; j < 8; ++j) { w0[j] = f2bf(xs[j]); w1[j] = f2bf(xs[j + 8]); }
            short* dst = &K_lds[kr][ksg * 16];
            *(bf16x8*)dst       = w0;
            *(bf16x8*)(dst + 8) = w1;
        }
        // ---- stage V2^T tile: Vt_lds[d][k] = bf16(V2[kt+k][d]) ----
        {
            const float4* p0 = (const float4*)(V2p + (size_t)(kt + 2 * k2) * D + dg * 8);
            const float4* p1 = (const float4*)(V2p + (size_t)(kt + 2 * k2 + 1) * D + dg * 8);
            float e[8], f[8];
            *(float4*)&e[0] = p0[0]; *(float4*)&e[4] = p0[1];
            *(float4*)&f[0] = p1[0]; *(float4*)&f[4] = p1[1];
            #pragma unroll
            for (int dd = 0; dd < 8; ++dd) {
                unsigned u = (unsigned)(unsigned short)f2bf(e[dd]) |
                             ((unsigned)(unsigned short)f2bf(f[dd]) << 16);
                *(unsigned*)&Vt_lds[dg * 8 + dd][2 * k2] = u;
            }
        }
        __syncthreads();

        // ---- scores S^T tile (64 keys x 16 q per wave) ----
        f32x4 accs[4];
        #pragma unroll
        for (int kb = 0; kb < 4; ++kb) {
            f32x4 a = (f32x4){0.f, 0.f, 0.f, 0.f};
            #pragma unroll
            for (int ds = 0; ds < 2; ++ds) {
                bf16x8 ak = *(const bf16x8*)&K_lds[kb * 16 + l15][ds * 32 + l4 * 8];
                a = __builtin_amdgcn_mfma_f32_16x16x32_bf16(ak, bq[ds], a, 0, 0, 0);
            }
            accs[kb] = a;
        }

        // ---- mask + scale + online softmax ----
        float s[16];
        float tmax = -1e30f;
        #pragma unroll
        for (int kb = 0; kb < 4; ++kb)
            #pragma unroll
            for (int jj = 0; jj < 4; ++jj) {
                float val = fmaf(accs[kb][jj], scaling, maskf[kt + kb * 16 + l4 * 4 + jj]);
                s[kb * 4 + jj] = val;
                tmax = fmaxf(tmax, val);
            }
        tmax = fmaxf(tmax, __shfl_xor(tmax, 16));
        tmax = fmaxf(tmax, __shfl_xor(tmax, 32));
        float mnew = fmaxf(m_run, tmax);
        float resc = __expf(m_run - mnew);
        float psum = 0.f;
        short pb[16];
        #pragma unroll
        for (int i = 0; i < 16; ++i) {
            float p = __expf(s[i] - mnew);
            psum += p;
            pb[i] = f2bf(p);
        }
        psum += __shfl_xor(psum, 16);
        psum += __shfl_xor(psum, 32);
        l_run = l_run * resc + psum;
        m_run = mnew;
        #pragma unroll
        for (int db = 0; db < 4; ++db)
            #pragma unroll
            for (int jj = 0; jj < 4; ++jj) acc_o[db][jj] *= resc;

        // ---- P^T to per-wave LDS, q-major: P2[q][key] ----
        #pragma unroll
        for (int kb = 0; kb < 4; ++kb) {
            s16x4 w = (s16x4){pb[kb * 4 + 0], pb[kb * 4 + 1], pb[kb * 4 + 2], pb[kb * 4 + 3]};
            *(s16x4*)&P2[wid][l15][kb * 16 + l4 * 4] = w;
        }
        bf16x8 bp[2];
        #pragma unroll
        for (int ks = 0; ks < 2; ++ks)
            bp[ks] = *(const bf16x8*)&P2[wid][l15][ks * 32 + l4 * 8];

        // ---- O^T += V2^T * P^T ----
        #pragma unroll
        for (int db = 0; db < 4; ++db) {
            #pragma unroll
            for (int ks = 0; ks < 2; ++ks) {
                bf16x8 av = *(const bf16x8*)&Vt_lds[db * 16 + l15][ks * 32 + l4 * 8];
                acc_o[db] = __builtin_amdgcn_mfma_f32_16x16x32_bf16(av, bp[ks], acc_o[db], 0, 0, 0);
            }
        }
    }

    // ---- channel gate: gate^T[e][q] = sum_d W[e][d] * (v1[q][d]*key[q][d]) ----
    f32x4 acc_g[4];
    #pragma unroll
    for (int i = 0; i < 4; ++i) acc_g[i] = (f32x4){0.f, 0.f, 0.f, 0.f};

    bf16x8 bam[2];
    #pragma unroll
    for (int ds = 0; ds < 2; ++ds) {
        const float4* p1 = (const float4*)(V1p + (size_t)qrow * D + ds * 32 + l4 * 8);
        const float4* pk = (const float4*)(Kp  + (size_t)qrow * D + ds * 32 + l4 * 8);
        float a[8], c[8];
        *(float4*)&a[0] = p1[0]; *(float4*)&a[4] = p1[1];
        *(float4*)&c[0] = pk[0]; *(float4*)&c[4] = pk[1];
        #pragma unroll
        for (int j = 0; j < 8; ++j) bam[ds][j] = f2bf(a[j] * c[j]);
    }
    #pragma unroll
    for (int eb = 0; eb < 4; ++eb) {
        #pragma unroll
        for (int ds = 0; ds < 2; ++ds) {
            bf16x8 aw;
            const float4* pw = (const float4*)(W + (size_t)(eb * 16 + l15) * D + ds * 32 + l4 * 8);
            float x[8];
            *(float4*)&x[0] = pw[0]; *(float4*)&x[4] = pw[1];
            #pragma unroll
            for (int j = 0; j < 8; ++j) aw[j] = f2bf(x[j]);
            acc_g[eb] = __builtin_amdgcn_mfma_f32_16x16x32_bf16(aw, bam[ds], acc_g[eb], 0, 0, 0);
        }
    }

    // ---- epilogue: out = (O / l) * sigmoid(gate + b), vectorized f32x4 stores ----
    float inv_l = 1.0f / l_run;
    #pragma unroll
    for (int db = 0; db < 4; ++db) {
        f32x4 o4;
        #pragma unroll
        for (int jj = 0; jj < 4; ++jj) {
            int d = db * 16 + l4 * 4 + jj;
            float o = acc_o[db][jj] * inv_l;
            float z = acc_g[db][jj] + bch[d];
            float gate = 1.0f / (1.0f + __expf(-z));
            o4[jj] = o * gate;
        }
        *(f32x4*)&out_attn[base + (size_t)qrow * D + db * 16 + l4 * 4] = o4;
    }
}

extern "C" void kernel_launch(void* const* d_in, const int* in_sizes, int n_in,
                              void* d_out, int out_size, void* d_ws, size_t ws_size,
                              hipStream_t stream) {
    const float* gv   = (const float*)d_in[0];
    const float* q2   = (const float*)d_in[1];
    const float* keyp = (const float*)d_in[2];
    const int*   mask = (const int*)  d_in[3];
    const float* v1   = (const float*)d_in[4];
    const float* v2   = (const float*)d_in[5];
    const float* W    = (const float*)d_in[6];
    const float* bch  = (const float*)d_in[7];
    float* out = (float*)d_out;

    dim3 grid(64, 16);   // (b*h, q-tile)
    aoa_attn_kernel<<<grid, 256, 0, stream>>>(gv, q2, keyp, mask, v1, v2, W, bch, out);
}

// Round 4
// 58.506 us; speedup vs baseline: 3.3762x; 1.3027x over previous
//
#include <hip/hip_runtime.h>

typedef __attribute__((ext_vector_type(4))) float f32x4;
typedef __attribute__((ext_vector_type(8))) short bf16x8;
typedef __attribute__((ext_vector_type(4))) short s16x4;
typedef __attribute__((ext_vector_type(4))) unsigned u32x4;
typedef __attribute__((ext_vector_type(2))) unsigned u32x2;

#define NEG_INF_F (-1000000000.0f)

__device__ inline unsigned bfbits(float f) {
    union { float f; unsigned u; } v; v.f = f;
    return (v.u + 0x7fffu + ((v.u >> 16) & 1u)) >> 16;
}
__device__ inline unsigned pkbf(float a, float b) {
    return bfbits(a) | (bfbits(b) << 16);
}
__device__ inline short f2bf(float f) { return (short)bfbits(f); }

// Block = 8 waves = one (b,h), 128 q rows. Wave w owns q rows [qt*128+w*16, +16).
// Orientation (verified R1/R2): S^T = K*Q^T ; O^T = V2^T*P^T ; gate^T = W*am^T
//   mfma_f32_16x16x32_bf16: C col=lane&15, row=(lane>>4)*4+j ; A[m][k]: m=l15, k=l4*8+j
// V2 staged in subtiled LDS [key>>2][d>>4][key&3][d&15] (128B units) and consumed
// via ds_read_b64_tr_b16 (HW transpose): lane l15 of group l4 gets column l15 of a
// 4x16 window -> av[j] = V2[key][d=db*16+l15]. Writes are linear b128, conflict-free.
__global__ __launch_bounds__(512) void aoa_attn_kernel(
    const float* __restrict__ gv,
    const float* __restrict__ q2,
    const float* __restrict__ keyp,
    const int*   __restrict__ maskp,
    const float* __restrict__ v1,
    const float* __restrict__ v2,
    const float* __restrict__ W,
    const float* __restrict__ bch,
    float* __restrict__ out)
{
    constexpr int S = 1024, D = 64;
    const int bh  = blockIdx.x;   // b*8 + h
    const int qt  = blockIdx.y;   // 0..7
    const int b   = bh >> 3;
    const int tid = threadIdx.x;
    const int wid = tid >> 6;
    const int lane = tid & 63;
    const int l15 = lane & 15;
    const int l4  = lane >> 4;

    float* out_attn = out + 512;
    if (bh == 0 && qt == 0) out[tid] = gv[tid];   // 512 threads = 512 floats

    __shared__ float maskf[S];           // 0 or NEG_INF
    __shared__ short Klds[64][72];       // [key][d], 144B row stride
    __shared__ short V2s[4096];          // subtiled: ((k>>2)*4+(d>>4))*64 + (k&3)*16 + (d&15)
    __shared__ short P2[8][16][72];      // per-wave [q_local][key_local]

    for (int i = tid; i < S; i += 512)
        maskf[i] = maskp[b * S + i] ? 0.0f : NEG_INF_F;

    const size_t base = (size_t)bh * S * D;
    const float* Qp  = q2   + base;
    const float* Kp  = keyp + base;
    const float* V1p = v1   + base;
    const float* V2p = v2   + base;

    const int qrow = qt * 128 + wid * 16 + l15;

    // Hoisted Q B-fragments: bq[ds][j] = Q[qrow][ds*32 + l4*8 + j]
    bf16x8 bq[2];
    #pragma unroll
    for (int ds = 0; ds < 2; ++ds) {
        const f32x4* p = (const f32x4*)(Qp + (size_t)qrow * D + ds * 32 + l4 * 8);
        f32x4 x0 = p[0], x1 = p[1];
        u32x4 u = (u32x4){pkbf(x0[0], x0[1]), pkbf(x0[2], x0[3]),
                          pkbf(x1[0], x1[1]), pkbf(x1[2], x1[3])};
        bq[ds] = *(bf16x8*)&u;
    }

    f32x4 acc_o[4];
    #pragma unroll
    for (int i = 0; i < 4; ++i) acc_o[i] = (f32x4){0.f, 0.f, 0.f, 0.f};
    float m_run = -1e30f, l_run = 0.0f;
    const float SC = 0.125f * 1.4426950408889634f;   // D^-0.5 * log2(e)

    // staging indices: thread -> (key, d0) 8 floats
    const int kk = tid >> 3;           // 0..63
    const int d0 = (tid & 7) << 3;     // 0..56
    const int v2wr = ((kk >> 2) * 4 + (d0 >> 4)) * 64 + (kk & 3) * 16 + (d0 & 8);
    const unsigned vbase = (unsigned)(size_t)V2s;

    for (int kt = 0; kt < S; kt += 64) {
        __syncthreads();   // previous tile fully consumed

        // ---- stage K tile (row-major bf16) ----
        {
            const f32x4* src = (const f32x4*)(Kp + (size_t)(kt + kk) * D + d0);
            f32x4 a0 = src[0], a1 = src[1];
            *(u32x4*)&Klds[kk][d0] = (u32x4){pkbf(a0[0], a0[1]), pkbf(a0[2], a0[3]),
                                             pkbf(a1[0], a1[1]), pkbf(a1[2], a1[3])};
        }
        // ---- stage V2 tile (subtiled for tr-read) ----
        {
            const f32x4* src = (const f32x4*)(V2p + (size_t)(kt + kk) * D + d0);
            f32x4 a0 = src[0], a1 = src[1];
            *(u32x4*)&V2s[v2wr] = (u32x4){pkbf(a0[0], a0[1]), pkbf(a0[2], a0[3]),
                                          pkbf(a1[0], a1[1]), pkbf(a1[2], a1[3])};
        }
        __syncthreads();

        // ---- scores S^T tile (64 keys x 16 q per wave) ----
        f32x4 accs[4];
        #pragma unroll
        for (int kb = 0; kb < 4; ++kb) {
            f32x4 a = (f32x4){0.f, 0.f, 0.f, 0.f};
            #pragma unroll
            for (int ds = 0; ds < 2; ++ds) {
                bf16x8 ak = *(const bf16x8*)&Klds[kb * 16 + l15][ds * 32 + l4 * 8];
                a = __builtin_amdgcn_mfma_f32_16x16x32_bf16(ak, bq[ds], a, 0, 0, 0);
            }
            accs[kb] = a;
        }

        // ---- mask + scale (exp2 domain) + online softmax with defer-max ----
        float s[16];
        float gmax[4];
        #pragma unroll
        for (int kb = 0; kb < 4; ++kb) {
            f32x4 mk = *(const f32x4*)&maskf[kt + kb * 16 + l4 * 4];
            float m0 = -1e30f;
            #pragma unroll
            for (int jj = 0; jj < 4; ++jj) {
                float val = fmaf(accs[kb][jj], SC, mk[jj]);
                s[kb * 4 + jj] = val;
                m0 = fmaxf(m0, val);
            }
            gmax[kb] = m0;
        }
        float tmax = fmaxf(fmaxf(gmax[0], gmax[1]), fmaxf(gmax[2], gmax[3]));
        tmax = fmaxf(tmax, __shfl_xor(tmax, 16));
        tmax = fmaxf(tmax, __shfl_xor(tmax, 32));

        if (__any(tmax > m_run + 8.0f)) {
            float mnew = fmaxf(m_run, tmax);
            float r = __builtin_amdgcn_exp2f(m_run - mnew);
            l_run *= r;
            #pragma unroll
            for (int db = 0; db < 4; ++db)
                #pragma unroll
                for (int jj = 0; jj < 4; ++jj) acc_o[db][jj] *= r;
            m_run = mnew;
        }

        float ps0 = 0.f, ps1 = 0.f;
        #pragma unroll
        for (int kb = 0; kb < 4; ++kb) {
            float p0 = __builtin_amdgcn_exp2f(s[kb * 4 + 0] - m_run);
            float p1 = __builtin_amdgcn_exp2f(s[kb * 4 + 1] - m_run);
            float p2 = __builtin_amdgcn_exp2f(s[kb * 4 + 2] - m_run);
            float p3 = __builtin_amdgcn_exp2f(s[kb * 4 + 3] - m_run);
            ps0 += p0 + p1; ps1 += p2 + p3;
            *(u32x2*)&P2[wid][l15][kb * 16 + l4 * 4] = (u32x2){pkbf(p0, p1), pkbf(p2, p3)};
        }
        float psum = ps0 + ps1;
        psum += __shfl_xor(psum, 16);
        psum += __shfl_xor(psum, 32);
        l_run += psum;

        bf16x8 bp[2];
        #pragma unroll
        for (int ks = 0; ks < 2; ++ks)
            bp[ks] = *(const bf16x8*)&P2[wid][l15][ks * 32 + l4 * 8];

        // ---- O^T += V2^T * P^T, A-fragments via HW transpose read ----
        #pragma unroll
        for (int db = 0; db < 4; ++db) {
            s16x4 t00, t01, t10, t11;
            unsigned a0 = vbase + (unsigned)(((l4 * 8 + db) << 7) + (l15 << 3));
            unsigned a1 = a0 + 32 * 128;
            asm volatile("ds_read_b64_tr_b16 %0, %1"            : "=v"(t00) : "v"(a0));
            asm volatile("ds_read_b64_tr_b16 %0, %1 offset:512" : "=v"(t01) : "v"(a0));
            asm volatile("ds_read_b64_tr_b16 %0, %1"            : "=v"(t10) : "v"(a1));
            asm volatile("ds_read_b64_tr_b16 %0, %1 offset:512" : "=v"(t11) : "v"(a1));
            asm volatile("s_waitcnt lgkmcnt(0)");
            __builtin_amdgcn_sched_barrier(0);
            bf16x8 av0 = __builtin_shufflevector(t00, t01, 0, 1, 2, 3, 4, 5, 6, 7);
            bf16x8 av1 = __builtin_shufflevector(t10, t11, 0, 1, 2, 3, 4, 5, 6, 7);
            acc_o[db] = __builtin_amdgcn_mfma_f32_16x16x32_bf16(av0, bp[0], acc_o[db], 0, 0, 0);
            acc_o[db] = __builtin_amdgcn_mfma_f32_16x16x32_bf16(av1, bp[1], acc_o[db], 0, 0, 0);
        }
    }

    // ---- channel gate: gate^T[e][q] = sum_d W[e][d] * (v1[q][d]*key[q][d]) ----
    f32x4 acc_g[4];
    #pragma unroll
    for (int i = 0; i < 4; ++i) acc_g[i] = (f32x4){0.f, 0.f, 0.f, 0.f};

    bf16x8 bam[2];
    #pragma unroll
    for (int ds = 0; ds < 2; ++ds) {
        const f32x4* p1 = (const f32x4*)(V1p + (size_t)qrow * D + ds * 32 + l4 * 8);
        const f32x4* pk = (const f32x4*)(Kp  + (size_t)qrow * D + ds * 32 + l4 * 8);
        f32x4 a0 = p1[0], a1 = p1[1], c0 = pk[0], c1 = pk[1];
        u32x4 u = (u32x4){pkbf(a0[0] * c0[0], a0[1] * c0[1]), pkbf(a0[2] * c0[2], a0[3] * c0[3]),
                          pkbf(a1[0] * c1[0], a1[1] * c1[1]), pkbf(a1[2] * c1[2], a1[3] * c1[3])};
        bam[ds] = *(bf16x8*)&u;
    }
    #pragma unroll
    for (int eb = 0; eb < 4; ++eb) {
        #pragma unroll
        for (int ds = 0; ds < 2; ++ds) {
            const f32x4* pw = (const f32x4*)(W + (size_t)(eb * 16 + l15) * D + ds * 32 + l4 * 8);
            f32x4 x0 = pw[0], x1 = pw[1];
            u32x4 u = (u32x4){pkbf(x0[0], x0[1]), pkbf(x0[2], x0[3]),
                              pkbf(x1[0], x1[1]), pkbf(x1[2], x1[3])};
            bf16x8 aw = *(bf16x8*)&u;
            acc_g[eb] = __builtin_amdgcn_mfma_f32_16x16x32_bf16(aw, bam[ds], acc_g[eb], 0, 0, 0);
        }
    }

    // ---- epilogue: out = (O / l) * sigmoid(gate + b) ----
    float inv_l = 1.0f / l_run;
    #pragma unroll
    for (int db = 0; db < 4; ++db) {
        f32x4 o4;
        #pragma unroll
        for (int jj = 0; jj < 4; ++jj) {
            int d = db * 16 + l4 * 4 + jj;
            float o = acc_o[db][jj] * inv_l;
            float z = acc_g[db][jj] + bch[d];
            float gate = 1.0f / (1.0f + __expf(-z));
            o4[jj] = o * gate;
        }
        *(f32x4*)&out_attn[base + (size_t)qrow * D + db * 16 + l4 * 4] = o4;
    }
}

extern "C" void kernel_launch(void* const* d_in, const int* in_sizes, int n_in,
                              void* d_out, int out_size, void* d_ws, size_t ws_size,
                              hipStream_t stream) {
    const float* gv   = (const float*)d_in[0];
    const float* q2   = (const float*)d_in[1];
    const float* keyp = (const float*)d_in[2];
    const int*   mask = (const int*)  d_in[3];
    const float* v1   = (const float*)d_in[4];
    const float* v2   = (const float*)d_in[5];
    const float* W    = (const float*)d_in[6];
    const float* bch  = (const float*)d_in[7];
    float* out = (float*)d_out;

    dim3 grid(64, 8);   // (b*h, 128-row q-tile)
    aoa_attn_kernel<<<grid, 512, 0, stream>>>(gv, q2, keyp, mask, v1, v2, W, bch, out);
}

// Round 5
// 48.995 us; speedup vs baseline: 4.0316x; 1.1941x over previous
//
#include <hip/hip_runtime.h>

typedef __attribute__((ext_vector_type(4)))  float f32x4;
typedef __attribute__((ext_vector_type(16))) float f32x16;
typedef __attribute__((ext_vector_type(8)))  short bf16x8;
typedef __attribute__((ext_vector_type(4)))  unsigned u32x4;
typedef __attribute__((ext_vector_type(2)))  unsigned u32x2;

#define NEG_INF_F (-1000000000.0f)

__device__ inline unsigned bfbits(float f) {
    union { float f; unsigned u; } v; v.f = f;
    return (v.u + 0x7fffu + ((v.u >> 16) & 1u)) >> 16;
}
__device__ inline unsigned pkbf(float a, float b) {
    return bfbits(a) | (bfbits(b) << 16);
}

// Block = 8 warps x 32 q-rows = 256 q. Grid (64 bh, 4 qt) = 256 blocks = 1/CU.
// mfma_f32_32x32x16_bf16:
//   A[m][k]: m=lane&31, k=(lane>>5)*8+j ; B[k][n]: n=lane&31, k=(lane>>5)*8+j
//   C[m][n]: n=lane&31, m=crow(r,h)=(r&3)+8*(r>>2)+4*(lane>>5)   [m74/m101]
// QK^T swapped: S^T[key][q] = A(K) x B(Q) -> lane holds q=l31, 16 keys in regs.
// Softmax in-lane; P packed via cvt_pk + 2 permlane32_swap per k-step (T12).
// PV: O[q][d] = A(P) x B(Vt) ; Vt[d][k] staged transposed, conflict-free.
// Gate: gate[q][e] = A(v1*k) x B(W^T) -> same C layout as O; fused sigmoid.
__global__ __launch_bounds__(512) void aoa_attn_kernel(
    const float* __restrict__ gv,
    const float* __restrict__ q2,
    const float* __restrict__ keyp,
    const int*   __restrict__ maskp,
    const float* __restrict__ v1,
    const float* __restrict__ v2,
    const float* __restrict__ W,
    const float* __restrict__ bch,
    float* __restrict__ out)
{
    constexpr int S = 1024, D = 64;
    const int bh  = blockIdx.x;
    const int qt  = blockIdx.y;
    const int b   = bh >> 3;
    const int tid = threadIdx.x;
    const int wid = tid >> 6;
    const int lane = tid & 63;
    const int l31 = lane & 31;
    const int h   = lane >> 5;

    float* out_attn = out + 512;
    if (bh == 0 && qt == 0) out[tid] = gv[tid];

    __shared__ float maskf[S];          // 0 or NEG_INF
    __shared__ short Klds[64][72];      // [key][d] row-major, 144B stride
    __shared__ short Vt[64][72];        // [d][key] transposed, 144B stride
    __shared__ float Lw[8][32];         // per-warp 1/l per q

    for (int i = tid; i < S; i += 512)
        maskf[i] = maskp[b * S + i] ? 0.0f : NEG_INF_F;

    const size_t base = (size_t)bh * S * D;
    const float* Qp  = q2   + base;
    const float* Kp  = keyp + base;
    const float* V1p = v1   + base;
    const float* V2p = v2   + base;

    const int q0   = qt * 256 + wid * 32;
    const int qrow = q0 + l31;

    // Q B-fragments: bq[ds][j] = Q[qrow][ds*16 + h*8 + j]
    bf16x8 bq[4];
    #pragma unroll
    for (int ds = 0; ds < 4; ++ds) {
        const f32x4* p = (const f32x4*)(Qp + (size_t)qrow * D + ds * 16 + h * 8);
        f32x4 x0 = p[0], x1 = p[1];
        u32x4 u = (u32x4){pkbf(x0[0], x0[1]), pkbf(x0[2], x0[3]),
                          pkbf(x1[0], x1[1]), pkbf(x1[2], x1[3])};
        bq[ds] = *(bf16x8*)&u;
    }

    f32x16 acc_o[2];
    #pragma unroll
    for (int dh = 0; dh < 2; ++dh)
        #pragma unroll
        for (int r = 0; r < 16; ++r) acc_o[dh][r] = 0.0f;

    float m_run = -1e30f, l_run = 0.0f;
    const float SC = 0.125f * 1.4426950408889634f;   // D^-0.5 * log2(e)

    // staging indices
    const int kk  = tid >> 3;          // K row 0..63
    const int d0  = (tid & 7) << 3;    // K d-offset
    const int dcol = tid & 63;         // Vt d-column (== lane)
    const int kr0  = (tid >> 6) << 3;  // Vt key chunk = wid*8

    // prefetch regs (tile 0)
    f32x4 kA, kB;
    float vv[8];
    {
        const f32x4* src = (const f32x4*)(Kp + (size_t)kk * D + d0);
        kA = src[0]; kB = src[1];
        #pragma unroll
        for (int i = 0; i < 8; ++i) vv[i] = V2p[(size_t)(kr0 + i) * D + dcol];
    }

    for (int t = 0; t < 16; ++t) {
        const int kt = t * 64;
        __syncthreads();   // previous tile fully consumed
        *(u32x4*)&Klds[kk][d0] = (u32x4){pkbf(kA[0], kA[1]), pkbf(kA[2], kA[3]),
                                         pkbf(kB[0], kB[1]), pkbf(kB[2], kB[3])};
        *(u32x4*)&Vt[dcol][kr0] = (u32x4){pkbf(vv[0], vv[1]), pkbf(vv[2], vv[3]),
                                          pkbf(vv[4], vv[5]), pkbf(vv[6], vv[7])};
        __syncthreads();

        if (t < 15) {   // prefetch next tile (lands during compute)
            const int kn = kt + 64;
            const f32x4* src = (const f32x4*)(Kp + (size_t)(kn + kk) * D + d0);
            kA = src[0]; kB = src[1];
            #pragma unroll
            for (int i = 0; i < 8; ++i) vv[i] = V2p[(size_t)(kn + kr0 + i) * D + dcol];
        }

        // ---- QK^T: S^T[key][q], 2 subtiles of 32 keys ----
        f32x16 accs[2];
        #pragma unroll
        for (int sub = 0; sub < 2; ++sub) {
            f32x16 a;
            #pragma unroll
            for (int r = 0; r < 16; ++r) a[r] = 0.0f;
            #pragma unroll
            for (int ds = 0; ds < 4; ++ds) {
                bf16x8 ak = *(const bf16x8*)&Klds[sub * 32 + l31][ds * 16 + h * 8];
                a = __builtin_amdgcn_mfma_f32_32x32x16_bf16(ak, bq[ds], a, 0, 0, 0);
            }
            accs[sub] = a;
        }

        // ---- mask + scale + in-lane online softmax (32 keys/lane) ----
        float s[32];
        float tmax = -1e30f;
        #pragma unroll
        for (int sub = 0; sub < 2; ++sub)
            #pragma unroll
            for (int g = 0; g < 4; ++g) {
                f32x4 mk = *(const f32x4*)&maskf[kt + sub * 32 + g * 8 + h * 4];
                #pragma unroll
                for (int j = 0; j < 4; ++j) {
                    float val = fmaf(accs[sub][g * 4 + j], SC, mk[j]);
                    s[sub * 16 + g * 4 + j] = val;
                    tmax = fmaxf(tmax, val);
                }
            }
        tmax = fmaxf(tmax, __shfl_xor(tmax, 32));

        if (__any(tmax > m_run + 8.0f)) {   // defer-max (T13)
            float mnew = fmaxf(m_run, tmax);
            float r = __builtin_amdgcn_exp2f(m_run - mnew);
            l_run *= r;
            #pragma unroll
            for (int dh = 0; dh < 2; ++dh)
                #pragma unroll
                for (int r2 = 0; r2 < 16; ++r2) acc_o[dh][r2] *= r;
            m_run = mnew;
        }

        float psum = 0.0f;
        unsigned w[16];
        #pragma unroll
        for (int i = 0; i < 16; ++i) {
            float p0 = __builtin_amdgcn_exp2f(s[2 * i]     - m_run);
            float p1 = __builtin_amdgcn_exp2f(s[2 * i + 1] - m_run);
            psum += p0 + p1;
            w[i] = pkbf(p0, p1);
        }
        psum += __shfl_xor(psum, 32);
        l_run += psum;

        // ---- PV: O[q][d] += P x Vt ----
        #pragma unroll
        for (int sub = 0; sub < 2; ++sub) {
            #pragma unroll
            for (int t2 = 0; t2 < 2; ++t2) {
                const int wb = sub * 8 + t2 * 4;
                u32x2 r0 = __builtin_amdgcn_permlane32_swap(w[wb + 0], w[wb + 2], false, false);
                u32x2 r1 = __builtin_amdgcn_permlane32_swap(w[wb + 1], w[wb + 3], false, false);
                u32x4 ua = (u32x4){r0[0], r1[0], r0[1], r1[1]};   // u0,u1,u2,u3
                bf16x8 pa = *(bf16x8*)&ua;
                #pragma unroll
                for (int dh = 0; dh < 2; ++dh) {
                    bf16x8 bv = *(const bf16x8*)&Vt[dh * 32 + l31][sub * 32 + t2 * 16 + h * 8];
                    acc_o[dh] = __builtin_amdgcn_mfma_f32_32x32x16_bf16(pa, bv, acc_o[dh], 0, 0, 0);
                }
            }
        }
    }

    // ---- channel gate: gate[q][e] = sum_d am[q][d]*W[e][d], same layout as O ----
    f32x16 acc_g[2];
    #pragma unroll
    for (int eh = 0; eh < 2; ++eh)
        #pragma unroll
        for (int r = 0; r < 16; ++r) acc_g[eh][r] = 0.0f;

    bf16x8 bam[4];
    #pragma unroll
    for (int ds = 0; ds < 4; ++ds) {
        const f32x4* p1 = (const f32x4*)(V1p + (size_t)qrow * D + ds * 16 + h * 8);
        const f32x4* pk = (const f32x4*)(Kp  + (size_t)qrow * D + ds * 16 + h * 8);
        f32x4 a0 = p1[0], a1 = p1[1], c0 = pk[0], c1 = pk[1];
        u32x4 u = (u32x4){pkbf(a0[0] * c0[0], a0[1] * c0[1]), pkbf(a0[2] * c0[2], a0[3] * c0[3]),
                          pkbf(a1[0] * c1[0], a1[1] * c1[1]), pkbf(a1[2] * c1[2], a1[3] * c1[3])};
        bam[ds] = *(bf16x8*)&u;
    }
    #pragma unroll
    for (int eh = 0; eh < 2; ++eh) {
        #pragma unroll
        for (int ds = 0; ds < 4; ++ds) {
            const f32x4* pw = (const f32x4*)(W + (size_t)(eh * 32 + l31) * D + ds * 16 + h * 8);
            f32x4 x0 = pw[0], x1 = pw[1];
            u32x4 u = (u32x4){pkbf(x0[0], x0[1]), pkbf(x0[2], x0[3]),
                              pkbf(x1[0], x1[1]), pkbf(x1[2], x1[3])};
            bf16x8 bw = *(bf16x8*)&u;
            acc_g[eh] = __builtin_amdgcn_mfma_f32_32x32x16_bf16(bam[ds], bw, acc_g[eh], 0, 0, 0);
        }
    }

    // ---- epilogue ----
    Lw[wid][l31] = 1.0f / l_run;        // both halves write same value
    const float bv0 = bch[l31], bv1 = bch[32 + l31];
    #pragma unroll
    for (int dh = 0; dh < 2; ++dh) {
        const float bc = dh ? bv1 : bv0;
        #pragma unroll
        for (int r = 0; r < 16; ++r) {
            const int ql = (r & 3) + 8 * (r >> 2) + 4 * h;   // crow(r,h)
            float invl = Lw[wid][ql];
            float o = acc_o[dh][r] * invl;
            float z = acc_g[dh][r] + bc;
            float gate = 1.0f / (1.0f + __expf(-z));
            out_attn[base + (size_t)(q0 + ql) * D + dh * 32 + l31] = o * gate;
        }
    }
}

extern "C" void kernel_launch(void* const* d_in, const int* in_sizes, int n_in,
                              void* d_out, int out_size, void* d_ws, size_t ws_size,
                              hipStream_t stream) {
    const float* gv   = (const float*)d_in[0];
    const float* q2   = (const float*)d_in[1];
    const float* keyp = (const float*)d_in[2];
    const int*   mask = (const int*)  d_in[3];
    const float* v1   = (const float*)d_in[4];
    const float* v2   = (const float*)d_in[5];
    const float* W    = (const float*)d_in[6];
    const float* bch  = (const float*)d_in[7];
    float* out = (float*)d_out;

    dim3 grid(64, 4);   // (b*h, 256-row q-tile)
    aoa_attn_kernel<<<grid, 512, 0, stream>>>(gv, q2, keyp, mask, v1, v2, W, bch, out);
}

// Round 6
// 48.154 us; speedup vs baseline: 4.1020x; 1.0175x over previous
//
#include <hip/hip_runtime.h>
#include <hip/hip_bf16.h>

typedef __attribute__((ext_vector_type(4)))  float f32x4;
typedef __attribute__((ext_vector_type(16))) float f32x16;
typedef __attribute__((ext_vector_type(8)))  short bf16x8;
typedef __attribute__((ext_vector_type(4)))  unsigned u32x4;
typedef __attribute__((ext_vector_type(2)))  unsigned u32x2;

#define NEG_INF_F (-1000000000.0f)

// native bf16 RNE converts -> compiler emits v_cvt_pk_bf16_f32 (m240: scalar casts beat hand-rolled)
__device__ inline unsigned pkbf(float a, float b) {
    union { __hip_bfloat16 h; unsigned short u; } x, y;
    x.h = __float2bfloat16(a);
    y.h = __float2bfloat16(b);
    return (unsigned)x.u | ((unsigned)y.u << 16);
}

// Block = 8 warps x 32 q-rows = 256 q. Grid (64 bh, 4 qt) = 256 blocks = 1/CU.
// mfma_f32_32x32x16_bf16:
//   A[m][k]: m=lane&31, k=(lane>>5)*8+j ; B[k][n]: n=lane&31, k=(lane>>5)*8+j
//   C[m][n]: n=lane&31, m=crow(r,h)=(r&3)+8*(r>>2)+4*(lane>>5)
// QK^T swapped: S^T[key][q] -> lane holds q, 32 keys in regs. Softmax in-lane.
// P via cvt_pk + permlane32_swap (T12). PV B-operand from transposed Vt LDS.
// R6: double-buffered K/Vt (1 barrier/tile), loads issued at top of iter,
//     ds_write to alt buffer at tail (T14), setprio around MFMA (T5).
__global__ __launch_bounds__(512) void aoa_attn_kernel(
    const float* __restrict__ gv,
    const float* __restrict__ q2,
    const float* __restrict__ keyp,
    const int*   __restrict__ maskp,
    const float* __restrict__ v1,
    const float* __restrict__ v2,
    const float* __restrict__ W,
    const float* __restrict__ bch,
    float* __restrict__ out)
{
    constexpr int S = 1024, D = 64;
    const int bh  = blockIdx.x;
    const int qt  = blockIdx.y;
    const int b   = bh >> 3;
    const int tid = threadIdx.x;
    const int wid = tid >> 6;
    const int lane = tid & 63;
    const int l31 = lane & 31;
    const int h   = lane >> 5;

    float* out_attn = out + 512;
    if (bh == 0 && qt == 0) out[tid] = gv[tid];

    __shared__ float maskf[S];             // 0 or NEG_INF
    __shared__ short Klds[2][64][72];      // [buf][key][d], 144B stride
    __shared__ short Vt[2][64][72];        // [buf][d][key]
    __shared__ float Lw[8][32];            // per-warp 1/l per q

    for (int i = tid; i < S; i += 512)
        maskf[i] = maskp[b * S + i] ? 0.0f : NEG_INF_F;

    const size_t base = (size_t)bh * S * D;
    const float* Qp  = q2   + base;
    const float* Kp  = keyp + base;
    const float* V1p = v1   + base;
    const float* V2p = v2   + base;

    const int q0   = qt * 256 + wid * 32;
    const int qrow = q0 + l31;

    // Q B-fragments: bq[ds][j] = Q[qrow][ds*16 + h*8 + j]
    bf16x8 bq[4];
    #pragma unroll
    for (int ds = 0; ds < 4; ++ds) {
        const f32x4* p = (const f32x4*)(Qp + (size_t)qrow * D + ds * 16 + h * 8);
        f32x4 x0 = p[0], x1 = p[1];
        u32x4 u = (u32x4){pkbf(x0[0], x0[1]), pkbf(x0[2], x0[3]),
                          pkbf(x1[0], x1[1]), pkbf(x1[2], x1[3])};
        bq[ds] = *(bf16x8*)&u;
    }

    f32x16 acc_o[2];
    #pragma unroll
    for (int dh = 0; dh < 2; ++dh)
        #pragma unroll
        for (int r = 0; r < 16; ++r) acc_o[dh][r] = 0.0f;

    float m_run = -1e30f, l_run = 0.0f;
    const float SC = 0.125f * 1.4426950408889634f;   // D^-0.5 * log2(e)

    // staging indices
    const int kk   = tid >> 3;          // K row 0..63
    const int d0   = (tid & 7) << 3;    // K d-offset
    const int dcol = tid & 63;          // Vt d-column
    const int kr0  = (tid >> 6) << 3;   // Vt key chunk = wid*8

    // prologue: tile 0 -> regs -> buf 0
    f32x4 kA, kB;
    float vv[8];
    {
        const f32x4* src = (const f32x4*)(Kp + (size_t)kk * D + d0);
        kA = src[0]; kB = src[1];
        #pragma unroll
        for (int i = 0; i < 8; ++i) vv[i] = V2p[(size_t)(kr0 + i) * D + dcol];
    }
    *(u32x4*)&Klds[0][kk][d0] = (u32x4){pkbf(kA[0], kA[1]), pkbf(kA[2], kA[3]),
                                        pkbf(kB[0], kB[1]), pkbf(kB[2], kB[3])};
    *(u32x4*)&Vt[0][dcol][kr0] = (u32x4){pkbf(vv[0], vv[1]), pkbf(vv[2], vv[3]),
                                         pkbf(vv[4], vv[5]), pkbf(vv[6], vv[7])};
    int cur = 0;

    for (int t = 0; t < 16; ++t) {
        const int kt = t * 64;
        __syncthreads();   // buf[cur] visible; buf[cur^1] consumed (iter t-1)

        if (t < 15) {   // issue next tile's loads now; they land under compute
            const f32x4* src = (const f32x4*)(Kp + (size_t)(kt + 64 + kk) * D + d0);
            kA = src[0]; kB = src[1];
            #pragma unroll
            for (int i = 0; i < 8; ++i) vv[i] = V2p[(size_t)(kt + 64 + kr0 + i) * D + dcol];
        }

        // ---- QK^T: S^T[key][q], 2 subtiles of 32 keys ----
        f32x16 accs[2];
        __builtin_amdgcn_s_setprio(1);
        #pragma unroll
        for (int sub = 0; sub < 2; ++sub) {
            f32x16 a;
            #pragma unroll
            for (int r = 0; r < 16; ++r) a[r] = 0.0f;
            #pragma unroll
            for (int ds = 0; ds < 4; ++ds) {
                bf16x8 ak = *(const bf16x8*)&Klds[cur][sub * 32 + l31][ds * 16 + h * 8];
                a = __builtin_amdgcn_mfma_f32_32x32x16_bf16(ak, bq[ds], a, 0, 0, 0);
            }
            accs[sub] = a;
        }
        __builtin_amdgcn_s_setprio(0);

        // ---- mask + scale + in-lane online softmax (32 keys/lane) ----
        float s[32];
        float tmax = -1e30f;
        #pragma unroll
        for (int sub = 0; sub < 2; ++sub)
            #pragma unroll
            for (int g = 0; g < 4; ++g) {
                f32x4 mk = *(const f32x4*)&maskf[kt + sub * 32 + g * 8 + h * 4];
                #pragma unroll
                for (int j = 0; j < 4; ++j) {
                    float val = fmaf(accs[sub][g * 4 + j], SC, mk[j]);
                    s[sub * 16 + g * 4 + j] = val;
                    tmax = fmaxf(tmax, val);
                }
            }
        tmax = fmaxf(tmax, __shfl_xor(tmax, 32));

        if (__any(tmax > m_run + 8.0f)) {   // defer-max (T13)
            float mnew = fmaxf(m_run, tmax);
            float r = __builtin_amdgcn_exp2f(m_run - mnew);
            l_run *= r;
            #pragma unroll
            for (int dh = 0; dh < 2; ++dh)
                #pragma unroll
                for (int r2 = 0; r2 < 16; ++r2) acc_o[dh][r2] *= r;
            m_run = mnew;
        }

        float psum = 0.0f;
        unsigned w[16];
        #pragma unroll
        for (int i = 0; i < 16; ++i) {
            float p0 = __builtin_amdgcn_exp2f(s[2 * i]     - m_run);
            float p1 = __builtin_amdgcn_exp2f(s[2 * i + 1] - m_run);
            psum += p0 + p1;
            w[i] = pkbf(p0, p1);
        }
        psum += __shfl_xor(psum, 32);
        l_run += psum;

        // ---- PV: O[q][d] += P x Vt ----
        __builtin_amdgcn_s_setprio(1);
        #pragma unroll
        for (int sub = 0; sub < 2; ++sub) {
            #pragma unroll
            for (int t2 = 0; t2 < 2; ++t2) {
                const int wb = sub * 8 + t2 * 4;
                u32x2 r0 = __builtin_amdgcn_permlane32_swap(w[wb + 0], w[wb + 2], false, false);
                u32x2 r1 = __builtin_amdgcn_permlane32_swap(w[wb + 1], w[wb + 3], false, false);
                u32x4 ua = (u32x4){r0[0], r1[0], r0[1], r1[1]};
                bf16x8 pa = *(bf16x8*)&ua;
                #pragma unroll
                for (int dh = 0; dh < 2; ++dh) {
                    bf16x8 bv = *(const bf16x8*)&Vt[cur][dh * 32 + l31][sub * 32 + t2 * 16 + h * 8];
                    acc_o[dh] = __builtin_amdgcn_mfma_f32_32x32x16_bf16(pa, bv, acc_o[dh], 0, 0, 0);
                }
            }
        }
        __builtin_amdgcn_s_setprio(0);

        if (t < 15) {   // write next tile into alternate buffer (visible after next barrier)
            *(u32x4*)&Klds[cur ^ 1][kk][d0] = (u32x4){pkbf(kA[0], kA[1]), pkbf(kA[2], kA[3]),
                                                      pkbf(kB[0], kB[1]), pkbf(kB[2], kB[3])};
            *(u32x4*)&Vt[cur ^ 1][dcol][kr0] = (u32x4){pkbf(vv[0], vv[1]), pkbf(vv[2], vv[3]),
                                                       pkbf(vv[4], vv[5]), pkbf(vv[6], vv[7])};
        }
        cur ^= 1;
    }

    // ---- channel gate: gate[q][e] = sum_d am[q][d]*W[e][d], same C layout as O ----
    f32x16 acc_g[2];
    #pragma unroll
    for (int eh = 0; eh < 2; ++eh)
        #pragma unroll
        for (int r = 0; r < 16; ++r) acc_g[eh][r] = 0.0f;

    bf16x8 bam[4];
    #pragma unroll
    for (int ds = 0; ds < 4; ++ds) {
        const f32x4* p1 = (const f32x4*)(V1p + (size_t)qrow * D + ds * 16 + h * 8);
        const f32x4* pk = (const f32x4*)(Kp  + (size_t)qrow * D + ds * 16 + h * 8);
        f32x4 a0 = p1[0], a1 = p1[1], c0 = pk[0], c1 = pk[1];
        u32x4 u = (u32x4){pkbf(a0[0] * c0[0], a0[1] * c0[1]), pkbf(a0[2] * c0[2], a0[3] * c0[3]),
                          pkbf(a1[0] * c1[0], a1[1] * c1[1]), pkbf(a1[2] * c1[2], a1[3] * c1[3])};
        bam[ds] = *(bf16x8*)&u;
    }
    #pragma unroll
    for (int eh = 0; eh < 2; ++eh) {
        #pragma unroll
        for (int ds = 0; ds < 4; ++ds) {
            const f32x4* pw = (const f32x4*)(W + (size_t)(eh * 32 + l31) * D + ds * 16 + h * 8);
            f32x4 x0 = pw[0], x1 = pw[1];
            u32x4 u = (u32x4){pkbf(x0[0], x0[1]), pkbf(x0[2], x0[3]),
                              pkbf(x1[0], x1[1]), pkbf(x1[2], x1[3])};
            bf16x8 bw = *(bf16x8*)&u;
            acc_g[eh] = __builtin_amdgcn_mfma_f32_32x32x16_bf16(bam[ds], bw, acc_g[eh], 0, 0, 0);
        }
    }

    // ---- epilogue: out = (O/l) * sigmoid(gate + b) ----
    Lw[wid][l31] = 1.0f / l_run;
    __builtin_amdgcn_wave_barrier();
    const float bv0 = bch[l31], bv1 = bch[32 + l31];
    #pragma unroll
    for (int dh = 0; dh < 2; ++dh) {
        const float bc = dh ? bv1 : bv0;
        #pragma unroll
        for (int r = 0; r < 16; ++r) {
            const int ql = (r & 3) + 8 * (r >> 2) + 4 * h;   // crow(r,h)
            float invl = Lw[wid][ql];
            float o = acc_o[dh][r] * invl;
            float z = acc_g[dh][r] + bc;
            float gate = 1.0f / (1.0f + __expf(-z));
            out_attn[base + (size_t)(q0 + ql) * D + dh * 32 + l31] = o * gate;
        }
    }
}

extern "C" void kernel_launch(void* const* d_in, const int* in_sizes, int n_in,
                              void* d_out, int out_size, void* d_ws, size_t ws_size,
                              hipStream_t stream) {
    const float* gv   = (const float*)d_in[0];
    const float* q2   = (const float*)d_in[1];
    const float* keyp = (const float*)d_in[2];
    const int*   mask = (const int*)  d_in[3];
    const float* v1   = (const float*)d_in[4];
    const float* v2   = (const float*)d_in[5];
    const float* W    = (const float*)d_in[6];
    const float* bch  = (const float*)d_in[7];
    float* out = (float*)d_out;

    dim3 grid(64, 4);   // (b*h, 256-row q-tile)
    aoa_attn_kernel<<<grid, 512, 0, stream>>>(gv, q2, keyp, mask, v1, v2, W, bch, out);
}